// Round 1
// baseline (117.239 us; speedup 1.0000x reference)
//
#include <hip/hip_runtime.h>

#define N1 1024
#define N2 1024
#define CDIM 128
#define HDIM 256

// ws layout (floats):
//   Wx  [256][128]  @ 0        (= W1[:, :C]  @ Wsr)
//   Wy  [256][128]  @ 32768    (= W1[:, C:]  @ Wtg)
//   XhT [256][1024] @ 65536    (XhT[h][n] = (X @ Wx^T)[n][h] + b1[h])
//   YhT [256][1024] @ 327680   (YhT[h][n] = (Y @ Wy^T)[n][h])

// ---------------- K1: fold weights ----------------
// Wx[h][j] = sum_c W1[h][c]     * Wsr[c][j]
// Wy[h][j] = sum_c W1[h][C+c]   * Wtg[c][j]
__global__ __launch_bounds__(256) void fold_weights(
    const float* __restrict__ W1, const float* __restrict__ Wsr,
    const float* __restrict__ Wtg, float* __restrict__ Wx,
    float* __restrict__ Wy) {
  int id = blockIdx.x * 256 + threadIdx.x;   // 0 .. 2*256*128-1
  int m  = id / (HDIM * CDIM);
  int r  = id % (HDIM * CDIM);
  int h  = r / CDIM;
  int j  = r % CDIM;
  const float* Wm    = m ? Wtg : Wsr;
  const float* w1row = W1 + (size_t)h * HDIM + (m ? CDIM : 0);
  float acc = 0.f;
#pragma unroll 8
  for (int c = 0; c < CDIM; ++c)
    acc = fmaf(w1row[c], Wm[(size_t)c * CDIM + j], acc);
  (m ? Wy : Wx)[(size_t)h * CDIM + j] = acc;
}

// ---------------- K2: OutT[h][n] = sum_k A[n][k]*W[h][k] (+bias[h]) ----------------
// grid (16, 4, 2): x = n-tile (64), y = h-tile (64), z = which matrix
__global__ __launch_bounds__(256) void gemm_ht(
    const float* __restrict__ X, const float* __restrict__ Y,
    const float* __restrict__ Wx, const float* __restrict__ Wy,
    const float* __restrict__ b1, float* __restrict__ XhT,
    float* __restrict__ YhT) {
  const float* A = blockIdx.z ? Y : X;
  const float* W = blockIdx.z ? Wy : Wx;
  float*       O = blockIdx.z ? YhT : XhT;
  const bool useBias = (blockIdx.z == 0);

  __shared__ float Al[64][132];   // [n][k], pad 128->132 to break bank aliasing
  __shared__ float Wl[128][68];   // [k][h], pad 64->68 (272B rows keep 16B align)

  const int t  = threadIdx.x;
  const int n0 = blockIdx.x * 64;
  const int h0 = blockIdx.y * 64;

  // stage A tile: 64 x 128
#pragma unroll
  for (int it = 0; it < 8; ++it) {
    int row = it * 8 + (t >> 5);
    int col = (t & 31) * 4;
    *(float4*)(&Al[row][col]) =
        *(const float4*)(&A[(size_t)(n0 + row) * CDIM + col]);
  }
  // stage W tile transposed: [k][h]
#pragma unroll
  for (int it = 0; it < 8; ++it) {
    int h = it * 8 + (t >> 5);
    int k = (t & 31) * 4;
    float4 w = *(const float4*)(&W[(size_t)(h0 + h) * CDIM + k]);
    Wl[k + 0][h] = w.x;
    Wl[k + 1][h] = w.y;
    Wl[k + 2][h] = w.z;
    Wl[k + 3][h] = w.w;
  }
  __syncthreads();

  const int tx = t & 15;   // h micro (4)
  const int ty = t >> 4;   // n micro (4)
  float acc[4][4];
#pragma unroll
  for (int i = 0; i < 4; ++i)
#pragma unroll
    for (int j = 0; j < 4; ++j) acc[i][j] = 0.f;

  for (int k4 = 0; k4 < CDIM; k4 += 4) {
    float a_[4][4];
#pragma unroll
    for (int i = 0; i < 4; ++i) {
      float4 v = *(const float4*)(&Al[ty * 4 + i][k4]);
      a_[i][0] = v.x; a_[i][1] = v.y; a_[i][2] = v.z; a_[i][3] = v.w;
    }
#pragma unroll
    for (int kk = 0; kk < 4; ++kk) {
      float4 w = *(const float4*)(&Wl[k4 + kk][tx * 4]);
      float wj[4] = {w.x, w.y, w.z, w.w};
#pragma unroll
      for (int i = 0; i < 4; ++i)
#pragma unroll
        for (int j = 0; j < 4; ++j)
          acc[i][j] = fmaf(a_[i][kk], wj[j], acc[i][j]);
    }
  }

  // epilogue: OutT[h][n] (+bias)
#pragma unroll
  for (int j = 0; j < 4; ++j) {
    int h = h0 + tx * 4 + j;
    float b = useBias ? b1[h] : 0.f;
    float4 v = {acc[0][j] + b, acc[1][j] + b, acc[2][j] + b, acc[3][j] + b};
    *(float4*)(&O[(size_t)h * N1 + n0 + ty * 4]) = v;
  }
}

// ---------------- K3: pairwise interaction ----------------
// M[a][b] = b2 + sum_h relu(XhT[h][a] + YhT[h][b]) * W2[h]
// grid (16,16): 64x64 output tile per block, 256 thr, 4x4 micro-tile
__global__ __launch_bounds__(256) void pairwise(
    const float* __restrict__ XhT, const float* __restrict__ YhT,
    const float* __restrict__ W2, const float* __restrict__ b2,
    float* __restrict__ M) {
  __shared__ float Xl[64][64];   // [h][a]
  __shared__ float Yl[64][64];   // [h][b]

  const int t  = threadIdx.x;
  const int tx = t & 15;   // b micro
  const int ty = t >> 4;   // a micro
  const int b0 = blockIdx.x * 64;
  const int a0 = blockIdx.y * 64;

  float acc[4][4];
#pragma unroll
  for (int i = 0; i < 4; ++i)
#pragma unroll
    for (int j = 0; j < 4; ++j) acc[i][j] = 0.f;

  for (int hc = 0; hc < HDIM; hc += 64) {
    // stage 64 h-rows x 64 cols of each operand
#pragma unroll
    for (int it = 0; it < 4; ++it) {
      int hl = it * 16 + (t >> 4);
      int c4 = (t & 15) * 4;
      *(float4*)(&Xl[hl][c4]) =
          *(const float4*)(&XhT[(size_t)(hc + hl) * N1 + a0 + c4]);
      *(float4*)(&Yl[hl][c4]) =
          *(const float4*)(&YhT[(size_t)(hc + hl) * N2 + b0 + c4]);
    }
    __syncthreads();

    for (int h4 = 0; h4 < 64; h4 += 4) {
      float4 w4 = *(const float4*)(&W2[hc + h4]);   // wave-uniform
      float wh[4] = {w4.x, w4.y, w4.z, w4.w};
#pragma unroll
      for (int hh = 0; hh < 4; ++hh) {
        int h = h4 + hh;
        float4 xv = *(const float4*)(&Xl[h][ty * 4]);
        float4 yv = *(const float4*)(&Yl[h][tx * 4]);
        float xa[4] = {xv.x, xv.y, xv.z, xv.w};
        float yb[4] = {yv.x, yv.y, yv.z, yv.w};
#pragma unroll
        for (int i = 0; i < 4; ++i)
#pragma unroll
          for (int j = 0; j < 4; ++j) {
            float s = xa[i] + yb[j];
            acc[i][j] = fmaf(fmaxf(s, 0.f), wh[hh], acc[i][j]);
          }
      }
    }
    __syncthreads();
  }

  const float bb = b2[0];
#pragma unroll
  for (int i = 0; i < 4; ++i) {
    int a = a0 + ty * 4 + i;
    float4 v = {acc[i][0] + bb, acc[i][1] + bb, acc[i][2] + bb,
                acc[i][3] + bb};
    *(float4*)(&M[(size_t)a * N2 + b0 + tx * 4]) = v;
  }
}

// ---------------- launch ----------------
extern "C" void kernel_launch(void* const* d_in, const int* in_sizes, int n_in,
                              void* d_out, int out_size, void* d_ws,
                              size_t ws_size, hipStream_t stream) {
  const float* X   = (const float*)d_in[0];
  const float* Y   = (const float*)d_in[1];
  const float* Wsr = (const float*)d_in[2];
  const float* Wtg = (const float*)d_in[3];
  const float* W1  = (const float*)d_in[4];
  const float* b1  = (const float*)d_in[5];
  const float* W2  = (const float*)d_in[6];
  const float* b2  = (const float*)d_in[7];
  float* out = (float*)d_out;

  float* ws  = (float*)d_ws;
  float* Wx  = ws;
  float* Wy  = ws + 32768;
  float* XhT = ws + 65536;
  float* YhT = ws + 65536 + 262144;

  fold_weights<<<256, 256, 0, stream>>>(W1, Wsr, Wtg, Wx, Wy);
  gemm_ht<<<dim3(16, 4, 2), 256, 0, stream>>>(X, Y, Wx, Wy, b1, XhT, YhT);
  pairwise<<<dim3(16, 16), 256, 0, stream>>>(XhT, YhT, W2, b2, out);
}

// Round 2
// 112.169 us; speedup vs baseline: 1.0452x; 1.0452x over previous
//
#include <hip/hip_runtime.h>

#define N1 1024
#define N2 1024
#define CDIM 128
#define HDIM 256

// ws layout (floats):
//   Wx  [256][128]  @ 0        (= W1[:, :C] @ Wsr)
//   Wy  [256][128]  @ 32768    (= W1[:, C:] @ Wtg)
//   XhT [256][1024] @ 65536    (XhT[h][n] = (X @ Wx^T)[n][h] + b1[h])
//   YhT [256][1024] @ 327680
//   P0..P3 [1024][1024] @ 589824 + z*1048576   (h-split partial sums)

// ---------------- K1: fold weights ----------------
__global__ __launch_bounds__(256) void fold_weights(
    const float* __restrict__ W1, const float* __restrict__ Wsr,
    const float* __restrict__ Wtg, float* __restrict__ Wx,
    float* __restrict__ Wy) {
  int id = blockIdx.x * 256 + threadIdx.x;
  int m  = id / (HDIM * CDIM);
  int r  = id % (HDIM * CDIM);
  int h  = r / CDIM;
  int j  = r % CDIM;
  const float* Wm    = m ? Wtg : Wsr;
  const float* w1row = W1 + (size_t)h * HDIM + (m ? CDIM : 0);
  float acc = 0.f;
#pragma unroll 8
  for (int c = 0; c < CDIM; ++c)
    acc = fmaf(w1row[c], Wm[(size_t)c * CDIM + j], acc);
  (m ? Wy : Wx)[(size_t)h * CDIM + j] = acc;
}

// ---------------- K2: OutT[h][n] = sum_k A[n][k]*W[h][k] (+bias[h]) ----------------
__global__ __launch_bounds__(256) void gemm_ht(
    const float* __restrict__ X, const float* __restrict__ Y,
    const float* __restrict__ Wx, const float* __restrict__ Wy,
    const float* __restrict__ b1, float* __restrict__ XhT,
    float* __restrict__ YhT) {
  const float* A = blockIdx.z ? Y : X;
  const float* W = blockIdx.z ? Wy : Wx;
  float*       O = blockIdx.z ? YhT : XhT;
  const bool useBias = (blockIdx.z == 0);

  __shared__ float Al[64][132];
  __shared__ float Wl[128][68];

  const int t  = threadIdx.x;
  const int n0 = blockIdx.x * 64;
  const int h0 = blockIdx.y * 64;

#pragma unroll
  for (int it = 0; it < 8; ++it) {
    int row = it * 8 + (t >> 5);
    int col = (t & 31) * 4;
    *(float4*)(&Al[row][col]) =
        *(const float4*)(&A[(size_t)(n0 + row) * CDIM + col]);
  }
#pragma unroll
  for (int it = 0; it < 8; ++it) {
    int h = it * 8 + (t >> 5);
    int k = (t & 31) * 4;
    float4 w = *(const float4*)(&W[(size_t)(h0 + h) * CDIM + k]);
    Wl[k + 0][h] = w.x;
    Wl[k + 1][h] = w.y;
    Wl[k + 2][h] = w.z;
    Wl[k + 3][h] = w.w;
  }
  __syncthreads();

  const int tx = t & 15;
  const int ty = t >> 4;
  float acc[4][4];
#pragma unroll
  for (int i = 0; i < 4; ++i)
#pragma unroll
    for (int j = 0; j < 4; ++j) acc[i][j] = 0.f;

  for (int k4 = 0; k4 < CDIM; k4 += 4) {
    float a_[4][4];
#pragma unroll
    for (int i = 0; i < 4; ++i) {
      float4 v = *(const float4*)(&Al[ty * 4 + i][k4]);
      a_[i][0] = v.x; a_[i][1] = v.y; a_[i][2] = v.z; a_[i][3] = v.w;
    }
#pragma unroll
    for (int kk = 0; kk < 4; ++kk) {
      float4 w = *(const float4*)(&Wl[k4 + kk][tx * 4]);
      float wj[4] = {w.x, w.y, w.z, w.w};
#pragma unroll
      for (int i = 0; i < 4; ++i)
#pragma unroll
        for (int j = 0; j < 4; ++j)
          acc[i][j] = fmaf(a_[i][kk], wj[j], acc[i][j]);
    }
  }

#pragma unroll
  for (int j = 0; j < 4; ++j) {
    int h = h0 + tx * 4 + j;
    float b = useBias ? b1[h] : 0.f;
    float4 v = {acc[0][j] + b, acc[1][j] + b, acc[2][j] + b, acc[3][j] + b};
    *(float4*)(&O[(size_t)h * N1 + n0 + ty * 4]) = v;
  }
}

// ---------------- K3: pairwise partial over h-slice ----------------
// grid (16,16,4): 64x64 output tile, z = h-slice of 64.
// P_z[a][b] = sum_{h in slice} relu(XhT[h][a] + YhT[h][b]) * W2[h]
__global__ __launch_bounds__(256, 4) void pairwise_half(
    const float* __restrict__ XhT, const float* __restrict__ YhT,
    const float* __restrict__ W2, float* __restrict__ Pbase) {
  __shared__ float Xl[64][64];   // [h][a]
  __shared__ float Yl[64][64];   // [h][b]

  const int t  = threadIdx.x;
  const int b0 = blockIdx.x * 64;
  const int a0 = blockIdx.y * 64;
  const int hb = blockIdx.z * 64;
  float* P = Pbase + (size_t)blockIdx.z * ((size_t)N1 * N2);

  // stage entire 64-h slice once: 2 x 16 KB, 4 float4 per thread per matrix
#pragma unroll
  for (int it = 0; it < 4; ++it) {
    int idx = it * 256 + t;       // 0..1023
    int hl  = idx >> 4;           // 0..63
    int c4  = (idx & 15) * 4;     // 0..60
    *(float4*)(&Xl[hl][c4]) =
        *(const float4*)(&XhT[(size_t)(hb + hl) * N1 + a0 + c4]);
    *(float4*)(&Yl[hl][c4]) =
        *(const float4*)(&YhT[(size_t)(hb + hl) * N2 + b0 + c4]);
  }
  __syncthreads();

  const int tx = t & 15;   // b micro
  const int ty = t >> 4;   // a micro

  float acc[4][4];
#pragma unroll
  for (int i = 0; i < 4; ++i)
#pragma unroll
    for (int j = 0; j < 4; ++j) acc[i][j] = 0.f;

#pragma unroll 2
  for (int h4 = 0; h4 < 64; h4 += 4) {
    float4 w4 = *(const float4*)(&W2[hb + h4]);   // wave-uniform, L1-hot
    float wh[4] = {w4.x, w4.y, w4.z, w4.w};
#pragma unroll
    for (int hh = 0; hh < 4; ++hh) {
      float4 xv = *(const float4*)(&Xl[h4 + hh][ty * 4]);
      float4 yv = *(const float4*)(&Yl[h4 + hh][tx * 4]);
      float xa[4] = {xv.x, xv.y, xv.z, xv.w};
      float yb[4] = {yv.x, yv.y, yv.z, yv.w};
#pragma unroll
      for (int i = 0; i < 4; ++i)
#pragma unroll
        for (int j = 0; j < 4; ++j) {
          float s = xa[i] + yb[j];
          acc[i][j] = fmaf(fmaxf(s, 0.f), wh[hh], acc[i][j]);
        }
    }
  }

#pragma unroll
  for (int i = 0; i < 4; ++i) {
    int a = a0 + ty * 4 + i;
    float4 v = {acc[i][0], acc[i][1], acc[i][2], acc[i][3]};
    *(float4*)(&P[(size_t)a * N2 + b0 + tx * 4]) = v;
  }
}

// ---------------- K4: finalize out = P0+P1+P2+P3 + b2 ----------------
__global__ __launch_bounds__(256) void finalize(
    const float* __restrict__ P0, const float* __restrict__ P1,
    const float* __restrict__ P2, const float* __restrict__ P3,
    const float* __restrict__ b2, float* __restrict__ out) {
  int i4 = blockIdx.x * 256 + threadIdx.x;   // float4 index
  float4 a = ((const float4*)P0)[i4];
  float4 b = ((const float4*)P1)[i4];
  float4 c = ((const float4*)P2)[i4];
  float4 d = ((const float4*)P3)[i4];
  const float bb = b2[0];
  float4 o = {a.x + b.x + c.x + d.x + bb, a.y + b.y + c.y + d.y + bb,
              a.z + b.z + c.z + d.z + bb, a.w + b.w + c.w + d.w + bb};
  ((float4*)out)[i4] = o;
}

// ---------------- launch ----------------
extern "C" void kernel_launch(void* const* d_in, const int* in_sizes, int n_in,
                              void* d_out, int out_size, void* d_ws,
                              size_t ws_size, hipStream_t stream) {
  const float* X   = (const float*)d_in[0];
  const float* Y   = (const float*)d_in[1];
  const float* Wsr = (const float*)d_in[2];
  const float* Wtg = (const float*)d_in[3];
  const float* W1  = (const float*)d_in[4];
  const float* b1  = (const float*)d_in[5];
  const float* W2  = (const float*)d_in[6];
  const float* b2  = (const float*)d_in[7];
  float* out = (float*)d_out;

  float* ws  = (float*)d_ws;
  float* Wx  = ws;
  float* Wy  = ws + 32768;
  float* XhT = ws + 65536;
  float* YhT = ws + 65536 + 262144;
  float* P   = ws + 589824;   // 4 partials of 1M floats each

  fold_weights<<<256, 256, 0, stream>>>(W1, Wsr, Wtg, Wx, Wy);
  gemm_ht<<<dim3(16, 4, 2), 256, 0, stream>>>(X, Y, Wx, Wy, b1, XhT, YhT);
  pairwise_half<<<dim3(16, 16, 4), 256, 0, stream>>>(XhT, YhT, W2, P);
  finalize<<<1024, 256, 0, stream>>>(P, P + 1048576, P + 2097152,
                                     P + 3145728, b2, out);
}